// Round 7
// baseline (472.577 us; speedup 1.0000x reference)
//
#include <hip/hip_runtime.h>
#include <cstdint>
#include <cstddef>

#define NB 4
#define CH 256
#define SS 4096
#define EE 128
#define NSPLIT 2
#define KLEN (SS / NSPLIT)
#define NCHUNK (KLEN / 32)
#define QSCALE 0.08838834764831845f /* 1/sqrt(128) */

typedef __attribute__((ext_vector_type(8))) short bfrag;   // 8 bf16 = 4 VGPR
typedef __attribute__((ext_vector_type(4))) float f32x4;   // MFMA acc

__device__ __forceinline__ unsigned short f2bf(float f) {
  union { float f; unsigned int u; } v; v.f = f;
  unsigned int u = v.u;
  unsigned int r = u + 0x7FFFu + ((u >> 16) & 1u);  // RNE
  return (unsigned short)(r >> 16);
}
__device__ __forceinline__ unsigned int pack2bf(float lo, float hi) {
  return (unsigned int)f2bf(lo) | ((unsigned int)f2bf(hi) << 16);
}

// ---------------------------------------------------------------------------
// Pass 0: fused fp32 -> bf16 conversion of x + the three weight matrices
// ---------------------------------------------------------------------------
__global__ __launch_bounds__(256) void cvt_all(
    const float* __restrict__ x,   const float* __restrict__ thw,
    const float* __restrict__ phw, const float* __restrict__ pw,
    unsigned short* __restrict__ xb,   unsigned short* __restrict__ thwb,
    unsigned short* __restrict__ phwb, unsigned short* __restrict__ pwb)
{
  const int nx4 = NB * CH * SS / 4;
  const int nw4 = EE * CH / 4;
  const int np4 = CH * CH / 4;
  int i = blockIdx.x * 256 + threadIdx.x;
  const float* src; unsigned short* dst; int off;
  if      (i < nx4)                 { src = x;   dst = xb;   off = i; }
  else if (i < nx4 + nw4)           { src = thw; dst = thwb; off = i - nx4; }
  else if (i < nx4 + 2 * nw4)       { src = phw; dst = phwb; off = i - nx4 - nw4; }
  else if (i < nx4 + 2 * nw4 + np4) { src = pw;  dst = pwb;  off = i - nx4 - 2 * nw4; }
  else return;
  float4 v = reinterpret_cast<const float4*>(src)[off];
  ushort4 o;
  o.x = f2bf(v.x); o.y = f2bf(v.y); o.z = f2bf(v.z); o.w = f2bf(v.w);
  reinterpret_cast<ushort4*>(dst)[off] = o;
}

// ---------------------------------------------------------------------------
// Pass 1: z=0: Qt[n][s][e] = QSCALE * sum_c theta_w[e][c] * x[n][c][s]
//         z=1: Kt[n][s][e] =          sum_c phi_w[e][c]   * x[n][c][s]
// ---------------------------------------------------------------------------
__global__ __launch_bounds__(256) void pass1_qk(
    const unsigned short* __restrict__ xb,
    const unsigned short* __restrict__ thw,
    const unsigned short* __restrict__ phw,
    unsigned short* __restrict__ Qt,
    unsigned short* __restrict__ Kt)
{
  __shared__ unsigned short xT[64][CH + 8];
  const int t  = threadIdx.x;
  const int n  = blockIdx.y;
  const int s0 = blockIdx.x * 64;
  const int z  = blockIdx.z;

  {
    const int soff = (t & 15) * 4;
    const int c0   = t >> 4;
    const ushort4* xv = reinterpret_cast<const ushort4*>(
        xb + ((size_t)n * CH) * SS + s0);
    #pragma unroll
    for (int ci = 0; ci < 16; ++ci) {
      const int c = c0 + ci * 16;
      ushort4 v = xv[c * (SS / 4) + (soff >> 2)];
      xT[soff + 0][c] = v.x;
      xT[soff + 1][c] = v.y;
      xT[soff + 2][c] = v.z;
      xT[soff + 3][c] = v.w;
    }
  }
  __syncthreads();

  const int w    = t >> 6;
  const int lane = t & 63;
  const int q    = lane >> 4;
  const int mr   = lane & 15;

  bfrag a[8];
  {
    const bfrag* rp = reinterpret_cast<const bfrag*>(&xT[w * 16 + mr][0]);
    #pragma unroll
    for (int k = 0; k < 8; ++k) a[k] = rp[k * 4 + q];
  }

  const unsigned short* wsel = z ? phw : thw;
  unsigned short*       osel = z ? Kt  : Qt;
  const float           sc   = z ? 1.0f : QSCALE;
  const bfrag* wp = reinterpret_cast<const bfrag*>(wsel);
  #pragma unroll
  for (int nt = 0; nt < 8; ++nt) {
    f32x4 acc = {0.f, 0.f, 0.f, 0.f};
    #pragma unroll
    for (int k = 0; k < 8; ++k) {
      bfrag b = wp[(nt * 16 + mr) * (CH / 8) + k * 4 + q];
      acc = __builtin_amdgcn_mfma_f32_16x16x32_bf16(a[k], b, acc, 0, 0, 0);
    }
    #pragma unroll
    for (int i = 0; i < 4; ++i) {
      const int srow = s0 + w * 16 + q * 4 + i;
      osel[((size_t)n * SS + srow) * EE + nt * 16 + mr] = f2bf(acc[i] * sc);
    }
  }
}

// ---------------------------------------------------------------------------
// Pass 2: barrier-free, LDS-free flash attention. 256 thr = 4 independent
// waves; each wave owns 16 queries x all 256 channels for one key-split.
//   S^T = K @ Q^T (A=K, B=Q; same frag addressing as before, operands
//   swapped). C-layout: lane (q,mr) holds S[key=g*16+q*4+i][query=mr].
//   Softmax row-reduce = shfl_xor(16,32). P re-laid to PV A-operand via 8
//   register shuffles: dest lane (q,mr) needs keys 8q..8q+7 = batch (q>=2)
//   of src lanes ((2q)&3)*16+mr and +16.
// Grid (SS/64, NB, NSPLIT) = 512 blocks of 4 waves, zero LDS.
// ---------------------------------------------------------------------------
__global__ __launch_bounds__(256, 2) void pass2_attn(
    const unsigned short* __restrict__ Qt,
    const unsigned short* __restrict__ Kt,
    const unsigned short* __restrict__ xb,
    unsigned short* __restrict__ Osp,
    float* __restrict__ Msp,
    float* __restrict__ Lsp)
{
  const int t    = threadIdx.x;
  const int n    = blockIdx.y;
  const int z    = blockIdx.z;
  const int wt   = t >> 6;
  const int lane = t & 63;
  const int q    = lane >> 4;
  const int mr   = lane & 15;
  const int sq   = blockIdx.x * 64 + wt * 16;   // this wave's query base
  const int tbeg = z * KLEN;

  // Q as B-operand: B[n=query=mr][k=e=32kc+8q+j]
  bfrag qb[4];
  {
    const bfrag* qp = reinterpret_cast<const bfrag*>(
        Qt + ((size_t)n * SS + sq + mr) * EE);
    #pragma unroll
    for (int kc = 0; kc < 4; ++kc) qb[kc] = qp[kc * 4 + q];
  }

  f32x4 o_acc[16];
  #pragma unroll
  for (int nt = 0; nt < 16; ++nt) o_acc[nt] = (f32x4){0.f, 0.f, 0.f, 0.f};

  float m_run = -INFINITY, l_run = 0.f;

  // K as A-operand: A[m=key=g*16+mr][k=e], chunk 0 preloaded
  const unsigned short* kbase = Kt + ((size_t)n * SS + tbeg) * EE;
  bfrag kf[2][4];
  #pragma unroll
  for (int g = 0; g < 2; ++g) {
    const bfrag* kp = reinterpret_cast<const bfrag*>(kbase + (size_t)(g * 16 + mr) * EE);
    #pragma unroll
    for (int kc = 0; kc < 4; ++kc) kf[g][kc] = kp[kc * 4 + q];
  }

  // V row base for this lane (c = nt*16 + mr rows, contiguous along keys)
  const unsigned short* vbase = xb + ((size_t)n * CH + mr) * SS + tbeg;

  for (int ci = 0; ci < NCHUNK; ++ci) {
    // ---- V loads for this chunk: in flight across QK^T + softmax ----
    bfrag vf[16];
    #pragma unroll
    for (int nt = 0; nt < 16; ++nt)
      vf[nt] = reinterpret_cast<const bfrag*>(
          vbase + (size_t)ci * 32 + (size_t)nt * 16 * SS)[q];

    // ---- S^T = K @ Q^T, two 16-key groups ----
    f32x4 sg0 = {0.f, 0.f, 0.f, 0.f}, sg1 = {0.f, 0.f, 0.f, 0.f};
    #pragma unroll
    for (int kc = 0; kc < 4; ++kc)
      sg0 = __builtin_amdgcn_mfma_f32_16x16x32_bf16(kf[0][kc], qb[kc], sg0, 0, 0, 0);
    #pragma unroll
    for (int kc = 0; kc < 4; ++kc)
      sg1 = __builtin_amdgcn_mfma_f32_16x16x32_bf16(kf[1][kc], qb[kc], sg1, 0, 0, 0);

    // ---- prefetch K for next chunk (consumed next iter top) ----
    if (ci + 1 < NCHUNK) {
      const unsigned short* kb2 = kbase + (size_t)(ci + 1) * 32 * EE;
      #pragma unroll
      for (int g = 0; g < 2; ++g) {
        const bfrag* kp = reinterpret_cast<const bfrag*>(kb2 + (size_t)(g * 16 + mr) * EE);
        #pragma unroll
        for (int kc = 0; kc < 4; ++kc) kf[g][kc] = kp[kc * 4 + q];
      }
    }

    // ---- in-register online softmax (rows = queries, keyed by mr) ----
    float vmax = fmaxf(fmaxf(fmaxf(sg0[0], sg0[1]), fmaxf(sg0[2], sg0[3])),
                       fmaxf(fmaxf(sg1[0], sg1[1]), fmaxf(sg1[2], sg1[3])));
    vmax = fmaxf(vmax, __shfl_xor(vmax, 16, 64));
    vmax = fmaxf(vmax, __shfl_xor(vmax, 32, 64));
    const float m_new = fmaxf(m_run, vmax);
    float p0[4], p1[4], sum = 0.f;
    #pragma unroll
    for (int i = 0; i < 4; ++i) { p0[i] = __expf(sg0[i] - m_new); sum += p0[i]; }
    #pragma unroll
    for (int i = 0; i < 4; ++i) { p1[i] = __expf(sg1[i] - m_new); sum += p1[i]; }
    sum += __shfl_xor(sum, 16, 64);
    sum += __shfl_xor(sum, 32, 64);
    const float alpha = __expf(m_run - m_new);  // exp(-inf)=0 on first chunk
    m_run = m_new;
    l_run = l_run * alpha + sum;

    // ---- P: C-layout -> A-operand layout via 8 shuffles ----
    const unsigned int P0a = pack2bf(p0[0], p0[1]);
    const unsigned int P0b = pack2bf(p0[2], p0[3]);
    const unsigned int P1a = pack2bf(p1[0], p1[1]);
    const unsigned int P1b = pack2bf(p1[2], p1[3]);
    const int sA = (((2 * q) & 3) << 4) + mr;
    const int sB = sA + 16;
    const unsigned int a0 = __shfl(P0a, sA, 64), a1 = __shfl(P0b, sA, 64);
    const unsigned int a2 = __shfl(P1a, sA, 64), a3 = __shfl(P1b, sA, 64);
    const unsigned int b0 = __shfl(P0a, sB, 64), b1 = __shfl(P0b, sB, 64);
    const unsigned int b2 = __shfl(P1a, sB, 64), b3 = __shfl(P1b, sB, 64);
    const bool hi = (q >= 2);
    union { unsigned int u[4]; bfrag f; } pc;
    pc.u[0] = hi ? a2 : a0;
    pc.u[1] = hi ? a3 : a1;
    pc.u[2] = hi ? b2 : b0;
    pc.u[3] = hi ? b3 : b1;

    // ---- rescale O (rows q*4+i need alpha of query q*4+i), then PV ----
    float al[4];
    #pragma unroll
    for (int i = 0; i < 4; ++i) al[i] = __shfl(alpha, q * 4 + i, 64);
    #pragma unroll
    for (int nt = 0; nt < 16; ++nt)
      #pragma unroll
      for (int i = 0; i < 4; ++i) o_acc[nt][i] *= al[i];
    #pragma unroll
    for (int nt = 0; nt < 16; ++nt)
      o_acc[nt] = __builtin_amdgcn_mfma_f32_16x16x32_bf16(pc.f, vf[nt], o_acc[nt], 0, 0, 0);
  }

  // ---- epilogue: partial O (normalized by own l) + m, l ----
  const float invl = 1.0f / l_run;
  float inv[4];
  #pragma unroll
  for (int i = 0; i < 4; ++i) inv[i] = __shfl(invl, q * 4 + i, 64);
  #pragma unroll
  for (int nt = 0; nt < 16; ++nt) {
    const int c = nt * 16 + mr;
    #pragma unroll
    for (int i = 0; i < 4; ++i) {
      const int s = sq + q * 4 + i;
      Osp[((size_t)(n * NSPLIT + z) * SS + s) * CH + c] = f2bf(o_acc[nt][i] * inv[i]);
    }
  }
  if (lane < 16) {
    const size_t mi = (size_t)(n * NSPLIT + z) * SS + sq + lane;
    Msp[mi] = m_run;
    Lsp[mi] = l_run;
  }
}

// ---------------------------------------------------------------------------
// Pass 3: split combine folded into fp32 accumulators (no bf16 blend, no LDS):
//   out[o][s] = x[o][s] + w0[s]*(pw @ O0)[o][s] + w1[s]*(pw @ O1)[o][s]
// ---------------------------------------------------------------------------
__global__ __launch_bounds__(256) void pass3_proj(
    const unsigned short* __restrict__ Osp,
    const float* __restrict__ Msp,
    const float* __restrict__ Lsp,
    const unsigned short* __restrict__ pw,
    const float* __restrict__ x,
    float* __restrict__ out)
{
  const int t    = threadIdx.x;
  const int w    = t >> 6;
  const int lane = t & 63;
  const int q    = lane >> 4;
  const int mr   = lane & 15;
  const int n    = blockIdx.z;
  const int o0   = blockIdx.y * 64 + w * 16;
  const int s1   = blockIdx.x * 64;

  bfrag a[8];
  {
    const bfrag* ap = reinterpret_cast<const bfrag*>(pw + (o0 + mr) * CH);
    #pragma unroll
    for (int k = 0; k < 8; ++k) a[k] = ap[k * 4 + q];
  }

  #pragma unroll
  for (int nt = 0; nt < 4; ++nt) {
    const int srow = s1 + nt * 16 + mr;   // lane's col s (same for all 4 rows)
    const size_t i0 = (size_t)(n * NSPLIT + 0) * SS + srow;
    const size_t i1 = (size_t)(n * NSPLIT + 1) * SS + srow;
    const float m0 = Msp[i0], m1 = Msp[i1];
    const float l0 = Lsp[i0], l1 = Lsp[i1];
    const float mm = fmaxf(m0, m1);
    const float a0w = __expf(m0 - mm) * l0;
    const float a1w = __expf(m1 - mm) * l1;
    const float inv = 1.0f / (a0w + a1w);
    const float w0 = a0w * inv, w1 = a1w * inv;

    const bfrag* bp0 = reinterpret_cast<const bfrag*>(Osp + i0 * CH);
    const bfrag* bp1 = reinterpret_cast<const bfrag*>(Osp + i1 * CH);
    f32x4 acc0 = {0.f, 0.f, 0.f, 0.f}, acc1 = {0.f, 0.f, 0.f, 0.f};
    #pragma unroll
    for (int k = 0; k < 8; ++k)
      acc0 = __builtin_amdgcn_mfma_f32_16x16x32_bf16(a[k], bp0[k * 4 + q], acc0, 0, 0, 0);
    #pragma unroll
    for (int k = 0; k < 8; ++k)
      acc1 = __builtin_amdgcn_mfma_f32_16x16x32_bf16(a[k], bp1[k * 4 + q], acc1, 0, 0, 0);
    #pragma unroll
    for (int i = 0; i < 4; ++i) {
      const int o = o0 + q * 4 + i;
      const size_t idx = ((size_t)n * CH + o) * SS + srow;
      out[idx] = x[idx] + (w0 * acc0[i] + w1 * acc1[i]);
    }
  }
}

// ---------------------------------------------------------------------------
extern "C" void kernel_launch(void* const* d_in, const int* in_sizes, int n_in,
                              void* d_out, int out_size, void* d_ws, size_t ws_size,
                              hipStream_t stream) {
  const float* x   = (const float*)d_in[0];
  const float* thw = (const float*)d_in[1];
  const float* phw = (const float*)d_in[2];
  const float* pw  = (const float*)d_in[3];
  float* out = (float*)d_out;

  unsigned short* xb   = (unsigned short*)d_ws;               // 8 MB
  unsigned short* Osp  = xb + (size_t)NB * CH * SS;           // 16 MB (2 splits)
  unsigned short* Qt   = Osp + (size_t)NSPLIT * NB * SS * CH; // 4 MB
  unsigned short* Kt   = Qt + (size_t)NB * SS * EE;           // 4 MB
  unsigned short* thwb = Kt + (size_t)NB * SS * EE;           // 64 KB
  unsigned short* phwb = thwb + EE * CH;                      // 64 KB
  unsigned short* pwb  = phwb + EE * CH;                      // 128 KB
  float*          Msp  = (float*)(pwb + CH * CH);             // 128 KB
  float*          Lsp  = Msp + (size_t)NSPLIT * NB * SS;      // 128 KB

  const int nx4 = NB * CH * SS / 4;
  const int nw4 = EE * CH / 4;
  const int np4 = CH * CH / 4;
  const int tot4 = nx4 + 2 * nw4 + np4;
  cvt_all<<<(tot4 + 255) / 256, 256, 0, stream>>>(
      x, thw, phw, pw, xb, thwb, phwb, pwb);

  pass1_qk  <<<dim3(SS / 64, NB, 2),       256, 0, stream>>>(xb, thwb, phwb, Qt, Kt);
  pass2_attn<<<dim3(SS / 64, NB, NSPLIT),  256, 0, stream>>>(Qt, Kt, xb, Osp, Msp, Lsp);
  pass3_proj<<<dim3(SS / 64, CH / 64, NB), 256, 0, stream>>>(Osp, Msp, Lsp, pwb, x, out);
}